// Round 1
// baseline (360.228 us; speedup 1.0000x reference)
//
#include <hip/hip_runtime.h>

// LoRAConnector: B=4, T=2048, N=4, C=1024, A=8, nC=4096, SINKHORN_ITERS=20
//
// Design (round 1):
//  - grid = 2048 blocks x 256 threads; each block handles 4 consecutive tokens
//    (all in the same batch since T%4==0 -> one adapter per block).
//  - thread -> (g = tid&3: which token, l = tid>>2: d4-slice 0..63).
//    Threads tid..tid+3 share the same d-slice for 4 different tokens, so
//    phi loads are 4-way address-deduped inside each wave (phi L2 traffic /4).
//  - x held in 16 float4 regs; out[i,c4=k*64+l] needs x[j][c4] = reg j*4+k of
//    the SAME thread -> no LDS staging of x, x read exactly once from HBM.
//  - dots accumulate (w*x). phi; divide by rms after reduction.
//  - out[i,c] = sum_j (M[i,j] + H_post[i]*H_pre[j]) * x[j,c]  (pre-agg +
//    post-dist collapse into one 4x4 matrix W).
//  - sinkhorn: lane owns (i,j) of token g; row sum = shfl_xor 4,8;
//    col sum = shfl_xor 16,32; 20 iters; rcp approx is fine vs 0.25 absmax.

#define BT 8192        // B*T tokens
#define NC 4096        // N*C
#define NC4 1024       // NC/4

__global__ __launch_bounds__(256) void lora_connector_kernel(
    const float* __restrict__ x,
    const float* __restrict__ inw,
    const float* __restrict__ phi_pre,
    const float* __restrict__ phi_post,
    const float* __restrict__ phi_res,
    const float* __restrict__ b_pre,
    const float* __restrict__ b_post,
    const float* __restrict__ b_res,
    const float* __restrict__ alpha_pre,
    const float* __restrict__ alpha_post,
    const float* __restrict__ alpha_res,
    const int*   __restrict__ adapter_indices,
    float* __restrict__ out)
{
    const int tid = threadIdx.x;
    const int g   = tid & 3;        // which of the block's 4 tokens
    const int l   = tid >> 2;       // d4-slice 0..63
    const int tok = blockIdx.x * 4 + g;
    const int b   = blockIdx.x >> 9;          // tok / 2048, block-uniform
    const int idx = adapter_indices[b];

    const float4* __restrict__ x4p = (const float4*)x + (size_t)tok * NC4;
    const float4* __restrict__ w4p = (const float4*)inw + (size_t)idx * NC4;
    const float4* __restrict__ pp4 = (const float4*)(phi_pre  + (size_t)idx * (NC * 4));
    const float4* __restrict__ po4 = (const float4*)(phi_post + (size_t)idx * (NC * 4));
    const float4* __restrict__ pr4 = (const float4*)(phi_res  + (size_t)idx * (NC * 16));

    float4 xs[16];
    float acc[25];
    #pragma unroll
    for (int j = 0; j < 25; ++j) acc[j] = 0.0f;

    // ---- Phase 1: stream x,w,phi; accumulate sumsq + 24 dots of (w*x).phi ----
    #pragma unroll
    for (int m = 0; m < 16; ++m) {
        const int d4 = m * 64 + l;
        const float4 xv = x4p[d4];
        const float4 wv = w4p[d4];
        xs[m] = xv;
        acc[24] = fmaf(xv.x, xv.x, fmaf(xv.y, xv.y, fmaf(xv.z, xv.z, fmaf(xv.w, xv.w, acc[24]))));
        const float xw[4] = { xv.x * wv.x, xv.y * wv.y, xv.z * wv.z, xv.w * wv.w };
        #pragma unroll
        for (int e = 0; e < 4; ++e) {
            const int d = d4 * 4 + e;
            const float s = xw[e];
            const float4 a = pp4[d];
            acc[0] = fmaf(s, a.x, acc[0]);
            acc[1] = fmaf(s, a.y, acc[1]);
            acc[2] = fmaf(s, a.z, acc[2]);
            acc[3] = fmaf(s, a.w, acc[3]);
            const float4 p = po4[d];
            acc[4] = fmaf(s, p.x, acc[4]);
            acc[5] = fmaf(s, p.y, acc[5]);
            acc[6] = fmaf(s, p.z, acc[6]);
            acc[7] = fmaf(s, p.w, acc[7]);
            #pragma unroll
            for (int q = 0; q < 4; ++q) {
                const float4 r = pr4[d * 4 + q];
                acc[8 + q * 4 + 0] = fmaf(s, r.x, acc[8 + q * 4 + 0]);
                acc[8 + q * 4 + 1] = fmaf(s, r.y, acc[8 + q * 4 + 1]);
                acc[8 + q * 4 + 2] = fmaf(s, r.z, acc[8 + q * 4 + 2]);
                acc[8 + q * 4 + 3] = fmaf(s, r.w, acc[8 + q * 4 + 3]);
            }
        }
    }

    // ---- Phase 2a: intra-wave butterfly over lane bits 2..5 (16 slices/token) ----
    #pragma unroll
    for (int j = 0; j < 25; ++j) {
        float v = acc[j];
        v += __shfl_xor(v, 4);
        v += __shfl_xor(v, 8);
        v += __shfl_xor(v, 16);
        v += __shfl_xor(v, 32);
        acc[j] = v;
    }

    // ---- Phase 2b: cross-wave reduction via LDS ----
    __shared__ float red[4][4][26];
    const int wv = tid >> 6;
    const int lw = tid & 63;
    if ((lw >> 2) == 0) {            // lanes 0..3: lane == g
        #pragma unroll
        for (int j = 0; j < 25; ++j) red[wv][g][j] = acc[j];
    }
    __syncthreads();
    float tot[25];
    #pragma unroll
    for (int j = 0; j < 25; ++j)
        tot[j] = (red[0][g][j] + red[1][g][j]) + (red[2][g][j] + red[3][g][j]);

    // ---- Phase 2c: rms, gates, sinkhorn ----
    const float inv_rms = rsqrtf(tot[24] * (1.0f / 4096.0f) + 1e-5f);
    const float apre  = alpha_pre[idx];
    const float apost = alpha_post[idx];
    const float ares  = alpha_res[idx];

    float Hpre[4], Hpost[4];
    #pragma unroll
    for (int n = 0; n < 4; ++n) {
        const float zp = fmaf(apre,  tot[n]     * inv_rms, b_pre[idx * 4 + n]);
        Hpre[n]  = 1.0f / (1.0f + __expf(-zp));
        const float zq = fmaf(apost, tot[4 + n] * inv_rms, b_post[idx * 4 + n]);
        Hpost[n] = 2.0f / (1.0f + __expf(-zq));
    }

    // lane owns element (si,sj) of token g's 4x4 matrix
    const int s  = lw >> 2;          // 0..15
    const int sj = s & 3;
    const int si = s >> 2;
    float Mv = __expf(fmaf(ares, tot[8 + si * 4 + sj] * inv_rms,
                           b_res[idx * 16 + si * 4 + sj]));
    #pragma unroll
    for (int it = 0; it < 20; ++it) {
        float rs = Mv + __shfl_xor(Mv, 4);   // sum over j (lane bits 2,3)
        rs += __shfl_xor(rs, 8);
        Mv *= __builtin_amdgcn_rcpf(rs);
        float cs = Mv + __shfl_xor(Mv, 16);  // sum over i (lane bits 4,5)
        cs += __shfl_xor(cs, 32);
        Mv *= __builtin_amdgcn_rcpf(cs);
    }

    // gather full W[i][j] = M[i][j] + Hpost[i]*Hpre[j] for this thread's token
    float W[4][4];
    #pragma unroll
    for (int ss = 0; ss < 16; ++ss) {
        const float mm = __shfl(Mv, ss * 4 + g);
        W[ss >> 2][ss & 3] = fmaf(Hpost[ss >> 2], Hpre[ss & 3], mm);
    }

    // ---- Phase 3: out[i,c] = sum_j W[i][j] * x[j,c], all from registers ----
    float4* __restrict__ out4 = (float4*)out + (size_t)tok * NC4;
    #pragma unroll
    for (int k = 0; k < 4; ++k) {
        const int c4 = k * 64 + l;
        const float4 x0 = xs[0 * 4 + k];
        const float4 x1 = xs[1 * 4 + k];
        const float4 x2 = xs[2 * 4 + k];
        const float4 x3 = xs[3 * 4 + k];
        #pragma unroll
        for (int i = 0; i < 4; ++i) {
            float4 o;
            o.x = fmaf(W[i][0], x0.x, fmaf(W[i][1], x1.x, fmaf(W[i][2], x2.x, W[i][3] * x3.x)));
            o.y = fmaf(W[i][0], x0.y, fmaf(W[i][1], x1.y, fmaf(W[i][2], x2.y, W[i][3] * x3.y)));
            o.z = fmaf(W[i][0], x0.z, fmaf(W[i][1], x1.z, fmaf(W[i][2], x2.z, W[i][3] * x3.z)));
            o.w = fmaf(W[i][0], x0.w, fmaf(W[i][1], x1.w, fmaf(W[i][2], x2.w, W[i][3] * x3.w)));
            out4[i * 256 + c4] = o;
        }
    }
}

extern "C" void kernel_launch(void* const* d_in, const int* in_sizes, int n_in,
                              void* d_out, int out_size, void* d_ws, size_t ws_size,
                              hipStream_t stream) {
    const float* x         = (const float*)d_in[0];
    const float* inw       = (const float*)d_in[1];
    const float* phi_pre   = (const float*)d_in[2];
    const float* phi_post  = (const float*)d_in[3];
    const float* phi_res   = (const float*)d_in[4];
    const float* b_pre     = (const float*)d_in[5];
    const float* b_post    = (const float*)d_in[6];
    const float* b_res     = (const float*)d_in[7];
    const float* alpha_pre = (const float*)d_in[8];
    const float* alpha_post= (const float*)d_in[9];
    const float* alpha_res = (const float*)d_in[10];
    const int*   adapter   = (const int*)d_in[11];
    float* out = (float*)d_out;

    dim3 grid(BT / 4);   // 2048 blocks, 4 tokens each
    dim3 block(256);
    lora_connector_kernel<<<grid, block, 0, stream>>>(
        x, inw, phi_pre, phi_post, phi_res,
        b_pre, b_post, b_res,
        alpha_pre, alpha_post, alpha_res,
        adapter, out);
}